// Round 3
// baseline (101.897 us; speedup 1.0000x reference)
//
#include <hip/hip_runtime.h>
#include <math.h>

#define LSEQ 8192
#define CCH  256
#define SDIM 64
#define PCHUNK 256            // number of chunks
#define CLEN (LSEQ / PCHUNK)  // 32 steps per chunk
#define DT (1.0 / 16000.0)

// ---------------- Phase 0: per-(c,s) parameters in fp64, stored transposed [s][C] ----------------
__global__ void s4d_params(const float* __restrict__ lognegA,
                           const float* __restrict__ B,
                           const float* __restrict__ Cp,
                           float* __restrict__ rt,    // r[s*C + c]
                           float* __restrict__ wt,    // w[s*C + c]
                           float* __restrict__ rPt) { // r^CLEN [s*C + c]
    int idx = blockIdx.x * blockDim.x + threadIdx.x;
    if (idx >= CCH * SDIM) return;
    int c = idx / SDIM;
    int s = idx % SDIM;
    double A   = -exp((double)lognegA[idx]);
    double adt = A * DT;
    double r   = exp(adt);
    double Bd  = expm1(adt) * (double)B[idx] / A;   // expm1: avoid fp32 cancellation
    double w   = (double)Cp[idx] * Bd;
    rt [s * CCH + c] = (float)r;
    wt [s * CCH + c] = (float)w;
    rPt[s * CCH + c] = (float)exp(adt * (double)CLEN);
}

// ---------------- Phase 1: per-chunk local end states (zero init) ----------------
// wave = (cb, p); lane = channel within cb. 64 states per lane in registers.
__global__ __launch_bounds__(256, 1) void s4d_local(const float* __restrict__ x,
                                                    const float* __restrict__ rt,
                                                    float* __restrict__ st) {
    int wave = blockIdx.x * (blockDim.x >> 6) + (threadIdx.x >> 6);
    int lane = threadIdx.x & 63;
    int cb = wave >> 8;          // wave / PCHUNK : 0..3
    int p  = wave & (PCHUNK - 1);
    int c  = cb * 64 + lane;

    float rr[SDIM], h[SDIM];
#pragma unroll
    for (int s = 0; s < SDIM; ++s) {
        rr[s] = rt[s * CCH + c];
        h[s]  = 0.0f;
    }
    const float* xp = x + (size_t)(p * CLEN) * CCH + c;
#pragma unroll 2
    for (int i = 0; i < CLEN; ++i) {
        float xv = xp[(size_t)i * CCH];
#pragma unroll
        for (int s = 0; s < SDIM; ++s)
            h[s] = fmaf(rr[s], h[s], xv);
    }
#pragma unroll
    for (int s = 0; s < SDIM; ++s)
        st[(size_t)(s * PCHUNK + p) * CCH + c] = h[s];
}

// ---------------- Phase 2: sequential scan over chunks; in-place e -> carry-in ----------------
// wave = (s, cb); lane = channel. 256 waves, 256 dependent steps each.
__global__ void s4d_scan(const float* __restrict__ rPt,
                         float* __restrict__ st) {
    int wave = blockIdx.x * (blockDim.x >> 6) + (threadIdx.x >> 6);
    int lane = threadIdx.x & 63;
    int s  = wave >> 2;          // 0..63
    int cb = wave & 3;
    int c  = cb * 64 + lane;
    float rp = rPt[s * CCH + c];
    float state = 0.0f;
    for (int p = 0; p < PCHUNK; ++p) {
        size_t idx = (size_t)(s * PCHUNK + p) * CCH + c;
        float e = st[idx];
        st[idx] = state;                 // carry-in h0 for chunk p
        state = fmaf(rp, state, e);
    }
}

// ---------------- Phase 3: recompute with carry-in, emit y ----------------
__global__ __launch_bounds__(256, 1) void s4d_final(const float* __restrict__ x,
                                                    const float* __restrict__ rt,
                                                    const float* __restrict__ wt,
                                                    const float* __restrict__ st,
                                                    float* __restrict__ y) {
    int wave = blockIdx.x * (blockDim.x >> 6) + (threadIdx.x >> 6);
    int lane = threadIdx.x & 63;
    int cb = wave >> 8;
    int p  = wave & (PCHUNK - 1);
    int c  = cb * 64 + lane;

    float rr[SDIM], ww[SDIM], h[SDIM];
#pragma unroll
    for (int s = 0; s < SDIM; ++s) {
        rr[s] = rt[s * CCH + c];
        ww[s] = wt[s * CCH + c];
        h[s]  = st[(size_t)(s * PCHUNK + p) * CCH + c];
    }
    const float* xp = x + (size_t)(p * CLEN) * CCH + c;
    float*       yp = y + (size_t)(p * CLEN) * CCH + c;
#pragma unroll 2
    for (int i = 0; i < CLEN; ++i) {
        float xv = xp[(size_t)i * CCH];
        float acc0 = 0.0f, acc1 = 0.0f;
#pragma unroll
        for (int s = 0; s < SDIM; s += 2) {
            h[s]     = fmaf(rr[s],     h[s],     xv);
            acc0     = fmaf(ww[s],     h[s],     acc0);
            h[s + 1] = fmaf(rr[s + 1], h[s + 1], xv);
            acc1     = fmaf(ww[s + 1], h[s + 1], acc1);
        }
        yp[(size_t)i * CCH] = acc0 + acc1;
    }
}

extern "C" void kernel_launch(void* const* d_in, const int* in_sizes, int n_in,
                              void* d_out, int out_size, void* d_ws, size_t ws_size,
                              hipStream_t stream) {
    const float* x       = (const float*)d_in[0];
    const float* lognegA = (const float*)d_in[1];
    const float* B       = (const float*)d_in[2];
    const float* Cp      = (const float*)d_in[3];
    float* out = (float*)d_out;

    float* ws  = (float*)d_ws;
    float* rt  = ws;                      // C*S floats
    float* wt  = rt  + CCH * SDIM;
    float* rPt = wt  + CCH * SDIM;
    float* st  = rPt + CCH * SDIM;        // C*S*PCHUNK floats (~16.8 MB)

    // Phase 0: params (16384 threads)
    s4d_params<<<(CCH * SDIM + 255) / 256, 256, 0, stream>>>(lognegA, B, Cp, rt, wt, rPt);
    // Phase 1: local chunk scans. 1024 waves = 256 blocks x 256 threads
    s4d_local<<<(4 * PCHUNK) / 4, 256, 0, stream>>>(x, rt, st);
    // Phase 2: chunk-carry scan. 256 waves = 64 blocks
    s4d_scan<<<(SDIM * 4) / 4, 256, 0, stream>>>(rPt, st);
    // Phase 3: final pass. 1024 waves
    s4d_final<<<(4 * PCHUNK) / 4, 256, 0, stream>>>(x, rt, wt, st, out);
}

// Round 4
// 97.244 us; speedup vs baseline: 1.0478x; 1.0478x over previous
//
#include <hip/hip_runtime.h>
#include <math.h>

#define LSEQ 8192
#define CCH  256
#define SDIM 64
#define PCHUNK 256            // number of chunks
#define CLEN (LSEQ / PCHUNK)  // 32 steps per chunk
#define DT (1.0 / 16000.0)
#define SB 32                 // phase-2 prefetch batch

// ---------------- Phase 0: per-(c,s) parameters in fp64, stored transposed [s][C] ----------------
__global__ void s4d_params(const float* __restrict__ lognegA,
                           const float* __restrict__ B,
                           const float* __restrict__ Cp,
                           float* __restrict__ rt,    // r[s*C + c]
                           float* __restrict__ wt,    // w[s*C + c]
                           float* __restrict__ rPt) { // r^CLEN [s*C + c]
    int idx = blockIdx.x * blockDim.x + threadIdx.x;
    if (idx >= CCH * SDIM) return;
    int c = idx / SDIM;
    int s = idx % SDIM;
    double A   = -exp((double)lognegA[idx]);
    double adt = A * DT;
    double r   = exp(adt);
    double Bd  = expm1(adt) * (double)B[idx] / A;   // expm1: avoid fp32 cancellation
    double w   = (double)Cp[idx] * Bd;
    rt [s * CCH + c] = (float)r;
    wt [s * CCH + c] = (float)w;
    rPt[s * CCH + c] = (float)exp(adt * (double)CLEN);
}

// ---------------- Phase 1: per-chunk local end states (zero init) ----------------
// wave = (cb, p); lane = channel within cb. 64 states per lane in registers.
// x loads double-buffered 8-deep: 512 FMA-cycles cover each batch's latency.
__global__ __launch_bounds__(256, 1) void s4d_local(const float* __restrict__ x,
                                                    const float* __restrict__ rt,
                                                    float* __restrict__ st) {
    int wave = blockIdx.x * (blockDim.x >> 6) + (threadIdx.x >> 6);
    int lane = threadIdx.x & 63;
    int cb = wave >> 8;          // wave / PCHUNK : 0..3
    int p  = wave & (PCHUNK - 1);
    int c  = cb * 64 + lane;

    float rr[SDIM], h[SDIM];
#pragma unroll
    for (int s = 0; s < SDIM; ++s) {
        rr[s] = rt[s * CCH + c];
        h[s]  = 0.0f;
    }
    const float* xp = x + (size_t)(p * CLEN) * CCH + c;

    float xa[8], xb[8];
#pragma unroll
    for (int j = 0; j < 8; ++j) xa[j] = xp[(size_t)j * CCH];

#pragma unroll
    for (int i0 = 0; i0 < CLEN; i0 += 16) {
#pragma unroll
        for (int j = 0; j < 8; ++j) xb[j] = xp[(size_t)(i0 + 8 + j) * CCH];
#pragma unroll
        for (int j = 0; j < 8; ++j)
#pragma unroll
            for (int s = 0; s < SDIM; ++s)
                h[s] = fmaf(rr[s], h[s], xa[j]);
        if (i0 + 16 < CLEN) {
#pragma unroll
            for (int j = 0; j < 8; ++j) xa[j] = xp[(size_t)(i0 + 16 + j) * CCH];
        }
#pragma unroll
        for (int j = 0; j < 8; ++j)
#pragma unroll
            for (int s = 0; s < SDIM; ++s)
                h[s] = fmaf(rr[s], h[s], xb[j]);
    }
#pragma unroll
    for (int s = 0; s < SDIM; ++s)
        st[(size_t)(s * PCHUNK + p) * CCH + c] = h[s];
}

// ---------------- Phase 2: sequential scan over chunks; in-place e -> carry-in ----------------
// wave = (s, cb); lane = channel. 256 waves; 32-deep double-buffered prefetch
// turns 256 serial load latencies into ~8 exposures.
__global__ void s4d_scan(const float* __restrict__ rPt,
                         float* __restrict__ st) {
    int wave = blockIdx.x * (blockDim.x >> 6) + (threadIdx.x >> 6);
    int lane = threadIdx.x & 63;
    int s  = wave >> 2;          // 0..63
    int cb = wave & 3;
    int c  = cb * 64 + lane;
    float rp = rPt[s * CCH + c];
    float state = 0.0f;
    size_t base = (size_t)s * PCHUNK * CCH + c;

    float ea[SB], eb[SB];
#pragma unroll
    for (int j = 0; j < SB; ++j) ea[j] = st[base + (size_t)j * CCH];

    for (int p0 = 0; p0 < PCHUNK; p0 += 2 * SB) {
#pragma unroll
        for (int j = 0; j < SB; ++j) eb[j] = st[base + (size_t)(p0 + SB + j) * CCH];
#pragma unroll
        for (int j = 0; j < SB; ++j) {
            st[base + (size_t)(p0 + j) * CCH] = state;   // carry-in h0 for chunk p0+j
            state = fmaf(rp, state, ea[j]);
        }
        if (p0 + 2 * SB < PCHUNK) {
#pragma unroll
            for (int j = 0; j < SB; ++j) ea[j] = st[base + (size_t)(p0 + 2 * SB + j) * CCH];
        }
#pragma unroll
        for (int j = 0; j < SB; ++j) {
            st[base + (size_t)(p0 + SB + j) * CCH] = state;
            state = fmaf(rp, state, eb[j]);
        }
    }
}

// ---------------- Phase 3: recompute with carry-in, emit y ----------------
__global__ __launch_bounds__(256, 1) void s4d_final(const float* __restrict__ x,
                                                    const float* __restrict__ rt,
                                                    const float* __restrict__ wt,
                                                    const float* __restrict__ st,
                                                    float* __restrict__ y) {
    int wave = blockIdx.x * (blockDim.x >> 6) + (threadIdx.x >> 6);
    int lane = threadIdx.x & 63;
    int cb = wave >> 8;
    int p  = wave & (PCHUNK - 1);
    int c  = cb * 64 + lane;

    float rr[SDIM], ww[SDIM], h[SDIM];
#pragma unroll
    for (int s = 0; s < SDIM; ++s) {
        rr[s] = rt[s * CCH + c];
        ww[s] = wt[s * CCH + c];
        h[s]  = st[(size_t)(s * PCHUNK + p) * CCH + c];
    }
    const float* xp = x + (size_t)(p * CLEN) * CCH + c;
    float*       yp = y + (size_t)(p * CLEN) * CCH + c;

    float xa[8], xb[8];
#pragma unroll
    for (int j = 0; j < 8; ++j) xa[j] = xp[(size_t)j * CCH];

#pragma unroll
    for (int i0 = 0; i0 < CLEN; i0 += 16) {
#pragma unroll
        for (int j = 0; j < 8; ++j) xb[j] = xp[(size_t)(i0 + 8 + j) * CCH];
#pragma unroll
        for (int j = 0; j < 8; ++j) {
            float xv = xa[j];
            float acc0 = 0.0f, acc1 = 0.0f;
#pragma unroll
            for (int s = 0; s < SDIM; s += 2) {
                h[s]     = fmaf(rr[s],     h[s],     xv);
                acc0     = fmaf(ww[s],     h[s],     acc0);
                h[s + 1] = fmaf(rr[s + 1], h[s + 1], xv);
                acc1     = fmaf(ww[s + 1], h[s + 1], acc1);
            }
            yp[(size_t)(i0 + j) * CCH] = acc0 + acc1;
        }
        if (i0 + 16 < CLEN) {
#pragma unroll
            for (int j = 0; j < 8; ++j) xa[j] = xp[(size_t)(i0 + 16 + j) * CCH];
        }
#pragma unroll
        for (int j = 0; j < 8; ++j) {
            float xv = xb[j];
            float acc0 = 0.0f, acc1 = 0.0f;
#pragma unroll
            for (int s = 0; s < SDIM; s += 2) {
                h[s]     = fmaf(rr[s],     h[s],     xv);
                acc0     = fmaf(ww[s],     h[s],     acc0);
                h[s + 1] = fmaf(rr[s + 1], h[s + 1], xv);
                acc1     = fmaf(ww[s + 1], h[s + 1], acc1);
            }
            yp[(size_t)(i0 + 8 + j) * CCH] = acc0 + acc1;
        }
    }
}

extern "C" void kernel_launch(void* const* d_in, const int* in_sizes, int n_in,
                              void* d_out, int out_size, void* d_ws, size_t ws_size,
                              hipStream_t stream) {
    const float* x       = (const float*)d_in[0];
    const float* lognegA = (const float*)d_in[1];
    const float* B       = (const float*)d_in[2];
    const float* Cp      = (const float*)d_in[3];
    float* out = (float*)d_out;

    float* ws  = (float*)d_ws;
    float* rt  = ws;                      // C*S floats
    float* wt  = rt  + CCH * SDIM;
    float* rPt = wt  + CCH * SDIM;
    float* st  = rPt + CCH * SDIM;        // S*PCHUNK*C floats (~16.8 MB)

    // Phase 0: params (16384 threads)
    s4d_params<<<(CCH * SDIM + 255) / 256, 256, 0, stream>>>(lognegA, B, Cp, rt, wt, rPt);
    // Phase 1: local chunk scans. 1024 waves = 256 blocks x 256 threads
    s4d_local<<<PCHUNK, 256, 0, stream>>>(x, rt, st);
    // Phase 2: chunk-carry scan. 256 waves = 64 blocks
    s4d_scan<<<SDIM, 256, 0, stream>>>(rPt, st);
    // Phase 3: final pass. 1024 waves
    s4d_final<<<PCHUNK, 256, 0, stream>>>(x, rt, wt, st, out);
}